// Round 1
// baseline (293.466 us; speedup 1.0000x reference)
//
#include <hip/hip_runtime.h>
#include <hip/hip_bf16.h>

// Problem constants
#define BB 8
#define SS 2048
#define DD 256
#define HH 512
#define LL 3

// ---------------------------------------------------------------------------
// Kernel 0: M[k][t] = sum_d proj_w[d][k] * pe[d][t];  c[t] = sum_d proj_b[d]*pe[d][t]
// Mc layout: M interleaved [k*2+t] (512 floats), then c0,c1 at [512],[513]
// ---------------------------------------------------------------------------
__global__ void compute_M(const float* __restrict__ pw, const float* __restrict__ pb,
                          const float* __restrict__ pe, float* __restrict__ Mc)
{
    int k = threadIdx.x; // 0..255
    float a0 = 0.f, a1 = 0.f;
    for (int d = 0; d < DD; ++d) {
        float w = pw[d * DD + k];
        a0 += w * pe[2 * d];
        a1 += w * pe[2 * d + 1];
    }
    Mc[2 * k] = a0;
    Mc[2 * k + 1] = a1;
    if (k == 0) {
        float c0 = 0.f, c1 = 0.f;
        for (int d = 0; d < DD; ++d) {
            c0 += pb[d] * pe[2 * d];
            c1 += pb[d] * pe[2 * d + 1];
        }
        Mc[512] = c0;
        Mc[513] = c1;
    }
}

// ---------------------------------------------------------------------------
// Kernel 1: psi = normalize(x @ M + c) followed by the 7 diffusion rescales
// (force==0 because mask is identity; each step multiplies by r/(r+EPS)).
// Thread handling s==S-1 also computes h0 = final_psi @ hebb^T into ws.
// ---------------------------------------------------------------------------
__global__ void psi_kernel(const float* __restrict__ x, const float* __restrict__ Mc,
                           const float* __restrict__ hebb,
                           float* __restrict__ psi, float* __restrict__ h0)
{
    __shared__ float sM[516];
    int tid = threadIdx.x;
    for (int i = tid; i < 514; i += 256) sM[i] = Mc[i];
    __syncthreads();

    int rid = blockIdx.x * 256 + tid;       // 0 .. B*S-1
    int b = rid >> 11, s = rid & (SS - 1);
    const float4* xr = reinterpret_cast<const float4*>(x + (size_t)rid * DD);
    float a0 = sM[512], a1 = sM[513];
    #pragma unroll 8
    for (int i = 0; i < DD / 4; ++i) {
        float4 v = xr[i];
        int k2 = i * 8;
        a0 += v.x * sM[k2]     + v.y * sM[k2 + 2] + v.z * sM[k2 + 4] + v.w * sM[k2 + 6];
        a1 += v.x * sM[k2 + 1] + v.y * sM[k2 + 3] + v.z * sM[k2 + 5] + v.w * sM[k2 + 7];
    }
    float n = sqrtf(a0 * a0 + a1 * a1);
    float scale = 1.f / (n + 1e-8f);
    float r = n * scale;
    #pragma unroll
    for (int it = 0; it < 7; ++it) {
        float f = r / (r + 1e-8f);
        scale *= f;
        r *= f;
    }
    float2 pv;
    pv.x = a0 * scale;
    pv.y = a1 * scale;
    *reinterpret_cast<float2*>(psi + (size_t)rid * 2) = pv;

    if (s == SS - 1) {
        for (int j = 0; j < HH; ++j)
            h0[(size_t)b * HH + j] = pv.x * hebb[2 * j] + pv.y * hebb[2 * j + 1];
    }
}

// ---------------------------------------------------------------------------
// Kernel 2: A[b,i,j] = psi[b,i,:].psi[b,j,:] ; mask[b,i,j] = (i==j)
// One block per (b,i) row; 256 threads x 8 floats each for A and mask.
// ---------------------------------------------------------------------------
__global__ void a_mask_kernel(const float* __restrict__ psi,
                              float* __restrict__ A, float* __restrict__ M)
{
    int blk = blockIdx.x;                 // b*S + i
    int b = blk >> 11, i = blk & (SS - 1);
    int tid = threadIdx.x;
    float2 pi = *reinterpret_cast<const float2*>(psi + (size_t)blk * 2);
    int j0 = tid * 8;
    const float4* pr = reinterpret_cast<const float4*>(psi + ((size_t)b * SS + j0) * 2);
    float4 q0 = pr[0], q1 = pr[1], q2 = pr[2], q3 = pr[3];
    float4 o0, o1;
    o0.x = pi.x * q0.x + pi.y * q0.y;
    o0.y = pi.x * q0.z + pi.y * q0.w;
    o0.z = pi.x * q1.x + pi.y * q1.y;
    o0.w = pi.x * q1.z + pi.y * q1.w;
    o1.x = pi.x * q2.x + pi.y * q2.y;
    o1.y = pi.x * q2.z + pi.y * q2.w;
    o1.z = pi.x * q3.x + pi.y * q3.y;
    o1.w = pi.x * q3.z + pi.y * q3.w;
    size_t rb = (size_t)blk * SS + j0;
    *reinterpret_cast<float4*>(A + rb) = o0;
    *reinterpret_cast<float4*>(A + rb + 4) = o1;
    float4 m0, m1;
    m0.x = (i == j0    ) ? 1.f : 0.f;
    m0.y = (i == j0 + 1) ? 1.f : 0.f;
    m0.z = (i == j0 + 2) ? 1.f : 0.f;
    m0.w = (i == j0 + 3) ? 1.f : 0.f;
    m1.x = (i == j0 + 4) ? 1.f : 0.f;
    m1.y = (i == j0 + 5) ? 1.f : 0.f;
    m1.z = (i == j0 + 6) ? 1.f : 0.f;
    m1.w = (i == j0 + 7) ? 1.f : 0.f;
    *reinterpret_cast<float4*>(M + rb) = m0;
    *reinterpret_cast<float4*>(M + rb + 4) = m1;
}

// ---------------------------------------------------------------------------
// Generic tiny-batch (B=8) GEMM: out[b,j] = R[b,j] + act( bias[j] + LN?(X)[b,:] . W[j,:] )
//   - optional LN on X (and optional second LN stage), staged in dynamic LDS
//   - optional LN on residual R (stats only; values read from global)
//   - act: 0 = none, 1 = silu
//   - G lanes (power of 2) cooperate per output j, shuffle-reduced.
// Block = 256 threads. Grid = J*G/256 (>=1).
// ---------------------------------------------------------------------------
__global__ void head_mm(const float* __restrict__ X, int K,
                        const float* __restrict__ xlnw, const float* __restrict__ xlnb,
                        const float* __restrict__ xln2w, const float* __restrict__ xln2b,
                        const float* __restrict__ W, const float* __restrict__ bias,
                        const float* __restrict__ res,
                        const float* __restrict__ reslnw, const float* __restrict__ reslnb,
                        float* __restrict__ out, int J, int G, int act)
{
    extern __shared__ float sX[];           // 8*K floats when LN is active
    __shared__ float s_m[8], s_r[8], s_rm[8], s_rr[8];
    const int tid = threadIdx.x;
    const int row = tid >> 5, lane = tid & 31;   // 32 lanes per batch-row for stats
    const bool doLN = (xlnw != nullptr);
    const bool doRLN = (res != nullptr) && (reslnw != nullptr);

    if (doLN) {
        float s = 0.f, ss = 0.f;
        for (int k = lane; k < K; k += 32) {
            float v = X[row * K + k];
            s += v; ss += v * v;
        }
        for (int d = 16; d; d >>= 1) { s += __shfl_down(s, d); ss += __shfl_down(ss, d); }
        if (lane == 0) {
            float m = s / K;
            s_m[row] = m;
            s_r[row] = rsqrtf(ss / K - m * m + 1e-5f);
        }
    }
    if (doRLN) {
        float s = 0.f, ss = 0.f;
        for (int k = lane; k < J; k += 32) {
            float v = res[row * J + k];
            s += v; ss += v * v;
        }
        for (int d = 16; d; d >>= 1) { s += __shfl_down(s, d); ss += __shfl_down(ss, d); }
        if (lane == 0) {
            float m = s / J;
            s_rm[row] = m;
            s_rr[row] = rsqrtf(ss / J - m * m + 1e-5f);
        }
    }
    __syncthreads();

    if (doLN) {
        for (int idx = tid; idx < 8 * K; idx += 256) {
            int b = idx / K, k = idx - b * K;
            sX[idx] = (X[idx] - s_m[b]) * s_r[b] * xlnw[k] + xlnb[k];
        }
        __syncthreads();
        if (xln2w) {   // second LN stage (LN(LN(x)))
            float s = 0.f, ss = 0.f;
            for (int k = lane; k < K; k += 32) {
                float v = sX[row * K + k];
                s += v; ss += v * v;
            }
            for (int d = 16; d; d >>= 1) { s += __shfl_down(s, d); ss += __shfl_down(ss, d); }
            if (lane == 0) {
                float m = s / K;
                s_m[row] = m;
                s_r[row] = rsqrtf(ss / K - m * m + 1e-5f);
            }
            __syncthreads();
            for (int idx = tid; idx < 8 * K; idx += 256) {
                int b = idx / K, k = idx - b * K;
                sX[idx] = (sX[idx] - s_m[b]) * s_r[b] * xln2w[k] + xln2b[k];
            }
            __syncthreads();
        }
    }

    const float* __restrict__ Xp = doLN ? (const float*)sX : X;
    const int g = tid & (G - 1);
    const int jj = tid / G;
    const int j = blockIdx.x * (256 / G) + jj;

    float acc[8] = {0.f, 0.f, 0.f, 0.f, 0.f, 0.f, 0.f, 0.f};
    if (j < J) {
        const float4* W4 = reinterpret_cast<const float4*>(W + (size_t)j * K);
        const int K4 = K >> 2;
        for (int i4 = g; i4 < K4; i4 += G) {
            float4 w4 = W4[i4];
            int k = i4 << 2;
            #pragma unroll
            for (int b = 0; b < 8; ++b) {
                float4 xv = *reinterpret_cast<const float4*>(Xp + b * K + k);
                acc[b] = fmaf(w4.x, xv.x, acc[b]);
                acc[b] = fmaf(w4.y, xv.y, acc[b]);
                acc[b] = fmaf(w4.z, xv.z, acc[b]);
                acc[b] = fmaf(w4.w, xv.w, acc[b]);
            }
        }
    }
    for (int d = G >> 1; d; d >>= 1) {
        #pragma unroll
        for (int b = 0; b < 8; ++b) acc[b] += __shfl_down(acc[b], d);
    }
    if (g == 0 && j < J) {
        float bs = bias ? bias[j] : 0.f;
        #pragma unroll
        for (int b = 0; b < 8; ++b) {
            float v = acc[b] + bs;
            if (act) v = v / (1.f + expf(-v));   // silu
            if (res) {
                float rv = res[(size_t)b * J + j];
                if (reslnw) rv = (rv - s_rm[b]) * s_rr[b] * reslnw[j] + reslnb[j];
                v += rv;
            }
            out[(size_t)b * J + j] = v;
        }
    }
}

// ---------------------------------------------------------------------------
extern "C" void kernel_launch(void* const* d_in, const int* in_sizes, int n_in,
                              void* d_out, int out_size, void* d_ws, size_t ws_size,
                              hipStream_t stream)
{
    const float* x      = (const float*)d_in[0];
    const float* proj_w = (const float*)d_in[1];
    const float* proj_b = (const float*)d_in[2];
    const float* pe     = (const float*)d_in[3];
    const float* hebb   = (const float*)d_in[4];
    const float* ai_w   = (const float*)d_in[5];
    const float* ai_b   = (const float*)d_in[6];
    const float* ao_w   = (const float*)d_in[7];
    const float* ao_b   = (const float*)d_in[8];
    const float* f1_w   = (const float*)d_in[9];
    const float* f1_b   = (const float*)d_in[10];
    const float* f2_w   = (const float*)d_in[11];
    const float* f2_b   = (const float*)d_in[12];
    const float* ln1w   = (const float*)d_in[13];
    const float* ln1b   = (const float*)d_in[14];
    const float* ln2w   = (const float*)d_in[15];
    const float* ln2b   = (const float*)d_in[16];
    const float* nAw    = (const float*)d_in[17];
    const float* nAb    = (const float*)d_in[18];
    const float* nBw    = (const float*)d_in[19];
    const float* nBb    = (const float*)d_in[20];
    const float* p1w    = (const float*)d_in[21];
    const float* p1b    = (const float*)d_in[22];
    const float* p2w    = (const float*)d_in[23];
    const float* p2b    = (const float*)d_in[24];

    float* out   = (float*)d_out;
    // output layout: preds(8) | A(B*S*S) | mask(B*S*S) | psi(B*S*2)
    float* preds = out;
    float* A     = out + 8;
    float* Mask  = out + 8 + (size_t)BB * SS * SS;
    float* Psi   = out + 8 + (size_t)2 * BB * SS * SS;

    float* ws = (float*)d_ws;
    float* Mc = ws;            // 514 (pad to 640)
    float* T  = ws + 640;      // 8x512 pre-LN state (starts as h0)
    float* V  = ws + 4736;     // 8x512
    float* T1 = ws + 8832;     // 8x512
    float* F  = ws + 12928;    // 8x2048
    float* P  = ws + 29312;    // 8x256

    compute_M<<<1, 256, 0, stream>>>(proj_w, proj_b, pe, Mc);
    psi_kernel<<<(BB * SS) / 256, 256, 0, stream>>>(x, Mc, hebb, Psi, T);
    a_mask_kernel<<<BB * SS, 256, 0, stream>>>(Psi, A, Mask);

    for (int l = 0; l < LL; ++l) {
        const float* pxw = l ? ln2w + (l - 1) * HH : nullptr;
        const float* pxb = l ? ln2b + (l - 1) * HH : nullptr;
        // v = LN?(h) @ Wv^T + bv            (J=512, K=512, G=32 -> 64 blocks)
        head_mm<<<64, 256, (pxw ? 8 * HH * 4 : 0), stream>>>(
            T, HH, pxw, pxb, nullptr, nullptr,
            ai_w + ((size_t)l * 3 * HH + 2 * HH) * HH, ai_b + l * 3 * HH + 2 * HH,
            nullptr, nullptr, nullptr, V, HH, 32, 0);
        // t1 = LN?(T) + (v @ Wo^T + bo)     (J=512, K=512)
        head_mm<<<64, 256, 0, stream>>>(
            V, HH, nullptr, nullptr, nullptr, nullptr,
            ao_w + (size_t)l * HH * HH, ao_b + l * HH,
            T, pxw, pxb, T1, HH, 32, 0);
        // f = silu(LN(t1,ln1) @ W1^T + b1)  (J=2048, K=512, G=16 -> 128 blocks)
        head_mm<<<128, 256, 8 * HH * 4, stream>>>(
            T1, HH, ln1w + l * HH, ln1b + l * HH, nullptr, nullptr,
            f1_w + (size_t)l * 4 * HH * HH, f1_b + l * 4 * HH,
            nullptr, nullptr, nullptr, F, 4 * HH, 16, 1);
        // t2 = LN(t1,ln1) + (f @ W2^T + b2) (J=512, K=2048, G=64 -> 128 blocks)
        head_mm<<<128, 256, 0, stream>>>(
            F, 4 * HH, nullptr, nullptr, nullptr, nullptr,
            f2_w + (size_t)l * HH * 4 * HH, f2_b + l * HH,
            T1, ln1w + l * HH, ln1b + l * HH, T, HH, 64, 0);
    }
    // p = silu( LN(LN(t2,ln2[2]),normA) @ p1^T + p1_b )   (J=256, K=512)
    head_mm<<<32, 256, 8 * HH * 4, stream>>>(
        T, HH, ln2w + 2 * HH, ln2b + 2 * HH, nAw, nAb,
        p1w, p1b, nullptr, nullptr, nullptr, P, HH / 2, 32, 1);
    // preds = LN(p,normB) @ p2^T + p2_b                   (J=1, K=256)
    head_mm<<<1, 256, 8 * (HH / 2) * 4, stream>>>(
        P, HH / 2, nBw, nBb, nullptr, nullptr,
        p2w, p2b, nullptr, nullptr, nullptr, preds, 1, 32, 0);
}

// Round 2
// 249.361 us; speedup vs baseline: 1.1769x; 1.1769x over previous
//
#include <hip/hip_runtime.h>
#include <hip/hip_bf16.h>

// Problem constants
#define BB 8
#define SS 2048
#define DD 256
#define HH 512
#define LL 3

// ---------------------------------------------------------------------------
// Kernel 0: M[k][t] = sum_d proj_w[d][k] * pe[d][t];  c[t] = sum_d proj_b[d]*pe[d][t]
// Mc layout: M interleaved [k*2+t] (512 floats), then c0,c1 at [512],[513]
// Block 1024: 4 threads per k (d-quarters), shfl_xor reduce within 4-lane group.
// ---------------------------------------------------------------------------
__global__ void compute_M(const float* __restrict__ pw, const float* __restrict__ pb,
                          const float* __restrict__ pe, float* __restrict__ Mc)
{
    int tid = threadIdx.x;          // 0..1023
    int k = tid >> 2;               // 0..255
    int sub = tid & 3;              // d-quarter
    float a0 = 0.f, a1 = 0.f;
    #pragma unroll 8
    for (int d = sub * 64; d < sub * 64 + 64; ++d) {
        float w = pw[d * DD + k];
        a0 += w * pe[2 * d];
        a1 += w * pe[2 * d + 1];
    }
    a0 += __shfl_xor(a0, 1); a0 += __shfl_xor(a0, 2);
    a1 += __shfl_xor(a1, 1); a1 += __shfl_xor(a1, 2);
    if (sub == 0) {
        Mc[2 * k] = a0;
        Mc[2 * k + 1] = a1;
    }
    if (tid == 0) {
        float c0 = 0.f, c1 = 0.f;
        #pragma unroll 4
        for (int d = 0; d < DD; ++d) {
            c0 += pb[d] * pe[2 * d];
            c1 += pb[d] * pe[2 * d + 1];
        }
        Mc[512] = c0;
        Mc[513] = c1;
    }
}

// ---------------------------------------------------------------------------
// Kernel 1: psi = normalize(x @ M + c) followed by the 7 diffusion rescales
// (force==0 because mask is identity; each step multiplies by r/(r+EPS)).
// 4 lanes cooperate per row: 256 blocks x 256 threads, 64 rows/block.
// ---------------------------------------------------------------------------
__global__ void psi_kernel(const float* __restrict__ x, const float* __restrict__ Mc,
                           float* __restrict__ psi)
{
    __shared__ float sM[516];
    int tid = threadIdx.x;
    for (int i = tid; i < 514; i += 256) sM[i] = Mc[i];
    __syncthreads();

    int sub = tid & 3;
    int rloc = tid >> 2;                    // 0..63
    int rid = blockIdx.x * 64 + rloc;       // 0 .. B*S-1
    const float4* xr = reinterpret_cast<const float4*>(x + (size_t)rid * DD);
    float a0 = 0.f, a1 = 0.f;
    #pragma unroll
    for (int i = sub; i < DD / 4; i += 4) {
        float4 v = xr[i];
        int k2 = i * 8;
        a0 += v.x * sM[k2]     + v.y * sM[k2 + 2] + v.z * sM[k2 + 4] + v.w * sM[k2 + 6];
        a1 += v.x * sM[k2 + 1] + v.y * sM[k2 + 3] + v.z * sM[k2 + 5] + v.w * sM[k2 + 7];
    }
    a0 += __shfl_xor(a0, 1); a0 += __shfl_xor(a0, 2);
    a1 += __shfl_xor(a1, 1); a1 += __shfl_xor(a1, 2);

    if (sub == 0) {
        a0 += sM[512];  // note: bias must be added after reduction only once
        a1 += sM[513];
        float n = sqrtf(a0 * a0 + a1 * a1);
        float scale = 1.f / (n + 1e-8f);
        float r = n * scale;
        #pragma unroll
        for (int it = 0; it < 7; ++it) {
            float f = r / (r + 1e-8f);
            scale *= f;
            r *= f;
        }
        float2 pv;
        pv.x = a0 * scale;
        pv.y = a1 * scale;
        *reinterpret_cast<float2*>(psi + (size_t)rid * 2) = pv;
    }
}

// ---------------------------------------------------------------------------
// Kernel 1b: h0[b,j] = psi[b,S-1,0]*hebb[j,0] + psi[b,S-1,1]*hebb[j,1]
// ---------------------------------------------------------------------------
__global__ void h0_kernel(const float* __restrict__ psi, const float* __restrict__ hebb,
                          float* __restrict__ h0)
{
    int b = blockIdx.x;           // 0..7
    int j = threadIdx.x;          // 0..511
    float2 pv = *reinterpret_cast<const float2*>(psi + ((size_t)b * SS + SS - 1) * 2);
    h0[(size_t)b * HH + j] = pv.x * hebb[2 * j] + pv.y * hebb[2 * j + 1];
}

// ---------------------------------------------------------------------------
// Kernel 2: A[b,i,j] = psi[b,i,:].psi[b,j,:] ; mask[b,i,j] = (i==j)
// One block per (b,i) row. Dense stores: thread covers j=tid*4 and j=1024+tid*4.
// ---------------------------------------------------------------------------
__global__ void a_mask_kernel(const float* __restrict__ psi,
                              float* __restrict__ A, float* __restrict__ M)
{
    int blk = blockIdx.x;                 // b*S + i
    int b = blk >> 11, i = blk & (SS - 1);
    int tid = threadIdx.x;
    float2 pi = *reinterpret_cast<const float2*>(psi + (size_t)blk * 2);
    #pragma unroll
    for (int c = 0; c < 2; ++c) {
        int j0 = c * 1024 + tid * 4;
        const float4* pr = reinterpret_cast<const float4*>(psi + ((size_t)b * SS + j0) * 2);
        float4 q0 = pr[0], q1 = pr[1];
        float4 o;
        o.x = pi.x * q0.x + pi.y * q0.y;
        o.y = pi.x * q0.z + pi.y * q0.w;
        o.z = pi.x * q1.x + pi.y * q1.y;
        o.w = pi.x * q1.z + pi.y * q1.w;
        size_t rb = (size_t)blk * SS + j0;
        *reinterpret_cast<float4*>(A + rb) = o;
        float4 m;
        m.x = (i == j0    ) ? 1.f : 0.f;
        m.y = (i == j0 + 1) ? 1.f : 0.f;
        m.z = (i == j0 + 2) ? 1.f : 0.f;
        m.w = (i == j0 + 3) ? 1.f : 0.f;
        *reinterpret_cast<float4*>(M + rb) = m;
    }
}

// ---------------------------------------------------------------------------
// Generic tiny-batch (B=8) GEMM: out[b,j] = R[b,j] + act( bias[j] + LN?(X)[b,:] . W[j,:] )
//   - optional LN on X (and optional second LN stage), staged in dynamic LDS
//   - optional LN on residual R (stats only; values read from global)
//   - act: 0 = none, 1 = silu
//   - G lanes (power of 2) cooperate per output j, shuffle-reduced.
// Block = 256 threads. Grid = J*G/256 (>=1).
// ---------------------------------------------------------------------------
__global__ void head_mm(const float* __restrict__ X, int K,
                        const float* __restrict__ xlnw, const float* __restrict__ xlnb,
                        const float* __restrict__ xln2w, const float* __restrict__ xln2b,
                        const float* __restrict__ W, const float* __restrict__ bias,
                        const float* __restrict__ res,
                        const float* __restrict__ reslnw, const float* __restrict__ reslnb,
                        float* __restrict__ out, int J, int G, int act)
{
    extern __shared__ float sX[];           // 8*K floats when LN is active
    __shared__ float s_m[8], s_r[8], s_rm[8], s_rr[8];
    const int tid = threadIdx.x;
    const int row = tid >> 5, lane = tid & 31;   // 32 lanes per batch-row for stats
    const bool doLN = (xlnw != nullptr);
    const bool doRLN = (res != nullptr) && (reslnw != nullptr);

    if (doLN) {
        float s = 0.f, ss = 0.f;
        for (int k = lane; k < K; k += 32) {
            float v = X[row * K + k];
            s += v; ss += v * v;
        }
        for (int d = 16; d; d >>= 1) { s += __shfl_down(s, d); ss += __shfl_down(ss, d); }
        if (lane == 0) {
            float m = s / K;
            s_m[row] = m;
            s_r[row] = rsqrtf(ss / K - m * m + 1e-5f);
        }
    }
    if (doRLN) {
        float s = 0.f, ss = 0.f;
        for (int k = lane; k < J; k += 32) {
            float v = res[row * J + k];
            s += v; ss += v * v;
        }
        for (int d = 16; d; d >>= 1) { s += __shfl_down(s, d); ss += __shfl_down(ss, d); }
        if (lane == 0) {
            float m = s / J;
            s_rm[row] = m;
            s_rr[row] = rsqrtf(ss / J - m * m + 1e-5f);
        }
    }
    __syncthreads();

    if (doLN) {
        for (int idx = tid; idx < 8 * K; idx += 256) {
            int b = idx / K, k = idx - b * K;
            sX[idx] = (X[idx] - s_m[b]) * s_r[b] * xlnw[k] + xlnb[k];
        }
        __syncthreads();
        if (xln2w) {   // second LN stage (LN(LN(x)))
            float s = 0.f, ss = 0.f;
            for (int k = lane; k < K; k += 32) {
                float v = sX[row * K + k];
                s += v; ss += v * v;
            }
            for (int d = 16; d; d >>= 1) { s += __shfl_down(s, d); ss += __shfl_down(ss, d); }
            if (lane == 0) {
                float m = s / K;
                s_m[row] = m;
                s_r[row] = rsqrtf(ss / K - m * m + 1e-5f);
            }
            __syncthreads();
            for (int idx = tid; idx < 8 * K; idx += 256) {
                int b = idx / K, k = idx - b * K;
                sX[idx] = (sX[idx] - s_m[b]) * s_r[b] * xln2w[k] + xln2b[k];
            }
            __syncthreads();
        }
    }

    const float* __restrict__ Xp = doLN ? (const float*)sX : X;
    const int g = tid & (G - 1);
    const int jj = tid / G;
    const int j = blockIdx.x * (256 / G) + jj;

    float acc[8] = {0.f, 0.f, 0.f, 0.f, 0.f, 0.f, 0.f, 0.f};
    if (j < J) {
        const float4* W4 = reinterpret_cast<const float4*>(W + (size_t)j * K);
        const int K4 = K >> 2;
        for (int i4 = g; i4 < K4; i4 += G) {
            float4 w4 = W4[i4];
            int k = i4 << 2;
            #pragma unroll
            for (int b = 0; b < 8; ++b) {
                float4 xv = *reinterpret_cast<const float4*>(Xp + b * K + k);
                acc[b] = fmaf(w4.x, xv.x, acc[b]);
                acc[b] = fmaf(w4.y, xv.y, acc[b]);
                acc[b] = fmaf(w4.z, xv.z, acc[b]);
                acc[b] = fmaf(w4.w, xv.w, acc[b]);
            }
        }
    }
    for (int d = G >> 1; d; d >>= 1) {
        #pragma unroll
        for (int b = 0; b < 8; ++b) acc[b] += __shfl_down(acc[b], d);
    }
    if (g == 0 && j < J) {
        float bs = bias ? bias[j] : 0.f;
        #pragma unroll
        for (int b = 0; b < 8; ++b) {
            float v = acc[b] + bs;
            if (act) v = v / (1.f + expf(-v));   // silu
            if (res) {
                float rv = res[(size_t)b * J + j];
                if (reslnw) rv = (rv - s_rm[b]) * s_rr[b] * reslnw[j] + reslnb[j];
                v += rv;
            }
            out[(size_t)b * J + j] = v;
        }
    }
}

// ---------------------------------------------------------------------------
extern "C" void kernel_launch(void* const* d_in, const int* in_sizes, int n_in,
                              void* d_out, int out_size, void* d_ws, size_t ws_size,
                              hipStream_t stream)
{
    const float* x      = (const float*)d_in[0];
    const float* proj_w = (const float*)d_in[1];
    const float* proj_b = (const float*)d_in[2];
    const float* pe     = (const float*)d_in[3];
    const float* hebb   = (const float*)d_in[4];
    const float* ai_w   = (const float*)d_in[5];
    const float* ai_b   = (const float*)d_in[6];
    const float* ao_w   = (const float*)d_in[7];
    const float* ao_b   = (const float*)d_in[8];
    const float* f1_w   = (const float*)d_in[9];
    const float* f1_b   = (const float*)d_in[10];
    const float* f2_w   = (const float*)d_in[11];
    const float* f2_b   = (const float*)d_in[12];
    const float* ln1w   = (const float*)d_in[13];
    const float* ln1b   = (const float*)d_in[14];
    const float* ln2w   = (const float*)d_in[15];
    const float* ln2b   = (const float*)d_in[16];
    const float* nAw    = (const float*)d_in[17];
    const float* nAb    = (const float*)d_in[18];
    const float* nBw    = (const float*)d_in[19];
    const float* nBb    = (const float*)d_in[20];
    const float* p1w    = (const float*)d_in[21];
    const float* p1b    = (const float*)d_in[22];
    const float* p2w    = (const float*)d_in[23];
    const float* p2b    = (const float*)d_in[24];

    float* out   = (float*)d_out;
    // output layout: preds(8) | A(B*S*S) | mask(B*S*S) | psi(B*S*2)
    float* preds = out;
    float* A     = out + 8;
    float* Mask  = out + 8 + (size_t)BB * SS * SS;
    float* Psi   = out + 8 + (size_t)2 * BB * SS * SS;

    float* ws = (float*)d_ws;
    float* Mc = ws;            // 514 (pad to 640)
    float* T  = ws + 640;      // 8x512 pre-LN state (starts as h0)
    float* V  = ws + 4736;     // 8x512
    float* T1 = ws + 8832;     // 8x512
    float* F  = ws + 12928;    // 8x2048
    float* P  = ws + 29312;    // 8x256

    compute_M<<<1, 1024, 0, stream>>>(proj_w, proj_b, pe, Mc);
    psi_kernel<<<(BB * SS) / 64, 256, 0, stream>>>(x, Mc, Psi);
    h0_kernel<<<BB, HH, 0, stream>>>(Psi, hebb, T);
    a_mask_kernel<<<BB * SS, 256, 0, stream>>>(Psi, A, Mask);

    for (int l = 0; l < LL; ++l) {
        const float* pxw = l ? ln2w + (l - 1) * HH : nullptr;
        const float* pxb = l ? ln2b + (l - 1) * HH : nullptr;
        // v = LN?(h) @ Wv^T + bv            (J=512, K=512, G=32 -> 64 blocks)
        head_mm<<<64, 256, (pxw ? 8 * HH * 4 : 0), stream>>>(
            T, HH, pxw, pxb, nullptr, nullptr,
            ai_w + ((size_t)l * 3 * HH + 2 * HH) * HH, ai_b + l * 3 * HH + 2 * HH,
            nullptr, nullptr, nullptr, V, HH, 32, 0);
        // t1 = LN?(T) + (v @ Wo^T + bo)     (J=512, K=512)
        head_mm<<<64, 256, 0, stream>>>(
            V, HH, nullptr, nullptr, nullptr, nullptr,
            ao_w + (size_t)l * HH * HH, ao_b + l * HH,
            T, pxw, pxb, T1, HH, 32, 0);
        // f = silu(LN(t1,ln1) @ W1^T + b1)  (J=2048, K=512, G=16 -> 128 blocks)
        head_mm<<<128, 256, 8 * HH * 4, stream>>>(
            T1, HH, ln1w + l * HH, ln1b + l * HH, nullptr, nullptr,
            f1_w + (size_t)l * 4 * HH * HH, f1_b + l * 4 * HH,
            nullptr, nullptr, nullptr, F, 4 * HH, 16, 1);
        // t2 = LN(t1,ln1) + (f @ W2^T + b2) (J=512, K=2048, G=64 -> 128 blocks)
        head_mm<<<128, 256, 0, stream>>>(
            F, 4 * HH, nullptr, nullptr, nullptr, nullptr,
            f2_w + (size_t)l * HH * 4 * HH, f2_b + l * HH,
            T1, ln1w + l * HH, ln1b + l * HH, T, HH, 64, 0);
    }
    // p = silu( LN(LN(t2,ln2[2]),normA) @ p1^T + p1_b )   (J=256, K=512)
    head_mm<<<32, 256, 8 * HH * 4, stream>>>(
        T, HH, ln2w + 2 * HH, ln2b + 2 * HH, nAw, nAb,
        p1w, p1b, nullptr, nullptr, nullptr, P, HH / 2, 32, 1);
    // preds = LN(p,normB) @ p2^T + p2_b                   (J=1, K=256)
    head_mm<<<1, 256, 8 * (HH / 2) * 4, stream>>>(
        P, HH / 2, nBw, nBb, nullptr, nullptr,
        p2w, p2b, nullptr, nullptr, nullptr, preds, 1, 32, 0);
}

// Round 3
// 239.809 us; speedup vs baseline: 1.2237x; 1.0398x over previous
//
#include <hip/hip_runtime.h>
#include <hip/hip_bf16.h>

// Problem constants
#define BB 8
#define SS 2048
#define DD 256
#define HH 512
#define LL 3
#define NROWS (BB * SS)

// ---------------------------------------------------------------------------
// A/mask row worker: A[b,i,j] = psi[b,i,:].psi[b,j,:] ; mask = (i==j).
// One block (256 threads) per row; dense float4 stores.
// ---------------------------------------------------------------------------
__device__ __forceinline__ void amask_row(const float* __restrict__ psi,
                                          float* __restrict__ A, float* __restrict__ M,
                                          int blk)
{
    int tid = threadIdx.x;
    int b = blk >> 11, i = blk & (SS - 1);
    float2 pi = *reinterpret_cast<const float2*>(psi + (size_t)blk * 2);
    #pragma unroll
    for (int c = 0; c < 2; ++c) {
        int j0 = c * 1024 + tid * 4;
        const float4* pr = reinterpret_cast<const float4*>(psi + ((size_t)b * SS + j0) * 2);
        float4 q0 = pr[0], q1 = pr[1];
        float4 o;
        o.x = pi.x * q0.x + pi.y * q0.y;
        o.y = pi.x * q0.z + pi.y * q0.w;
        o.z = pi.x * q1.x + pi.y * q1.y;
        o.w = pi.x * q1.z + pi.y * q1.w;
        size_t rb = (size_t)blk * SS + j0;
        *reinterpret_cast<float4*>(A + rb) = o;
        float4 m;
        m.x = (i == j0    ) ? 1.f : 0.f;
        m.y = (i == j0 + 1) ? 1.f : 0.f;
        m.z = (i == j0 + 2) ? 1.f : 0.f;
        m.w = (i == j0 + 3) ? 1.f : 0.f;
        *reinterpret_cast<float4*>(M + rb) = m;
    }
}

// ---------------------------------------------------------------------------
// Kernel 0: M[k][t] = sum_d proj_w[d][k] * pe[d][t];  c[t] = sum_d proj_b[d]*pe[d][t]
// Mc layout: M interleaved [k*2+t] (512 floats), then c0,c1 at [512],[513]
// 1024 threads: tid&255 = k (coalesced loads), tid>>8 = d-quarter; LDS reduce.
// ---------------------------------------------------------------------------
__global__ void compute_M(const float* __restrict__ pw, const float* __restrict__ pb,
                          const float* __restrict__ pe, float* __restrict__ Mc)
{
    __shared__ float s0[4][256], s1[4][256];
    int tid = threadIdx.x;          // 0..1023
    int k = tid & 255;
    int sub = tid >> 8;             // 0..3
    float a0 = 0.f, a1 = 0.f;
    #pragma unroll 8
    for (int d = sub * 64; d < sub * 64 + 64; ++d) {
        float w = pw[d * DD + k];   // wave-contiguous in k
        a0 += w * pe[2 * d];        // d wave-uniform -> scalar broadcast
        a1 += w * pe[2 * d + 1];
    }
    s0[sub][k] = a0;
    s1[sub][k] = a1;
    __syncthreads();
    if (tid < 256) {
        Mc[2 * tid]     = s0[0][tid] + s0[1][tid] + s0[2][tid] + s0[3][tid];
        Mc[2 * tid + 1] = s1[0][tid] + s1[1][tid] + s1[2][tid] + s1[3][tid];
    }
    if (tid < 64) {
        float c0 = 0.f, c1 = 0.f;
        for (int d = tid; d < DD; d += 64) {
            c0 += pb[d] * pe[2 * d];
            c1 += pb[d] * pe[2 * d + 1];
        }
        #pragma unroll
        for (int dd = 32; dd; dd >>= 1) {
            c0 += __shfl_xor(c0, dd);
            c1 += __shfl_xor(c1, dd);
        }
        if (tid == 0) { Mc[512] = c0; Mc[513] = c1; }
    }
}

// ---------------------------------------------------------------------------
// Kernel 1: psi = normalize(x @ M + c) then 7 diffusion rescales (force==0).
// One wave per row (64 lanes x float4 = full 1KB row, fully coalesced).
// M fragment per lane lives in 2 float4 registers (read once from L2).
// Grid: NROWS/16 blocks x 256 threads; each wave does 4 rows.
// ---------------------------------------------------------------------------
__global__ void psi_kernel(const float* __restrict__ x, const float* __restrict__ Mc,
                           float* __restrict__ psi)
{
    int tid = threadIdx.x;
    int wave = tid >> 6, lane = tid & 63;
    const float4* Mc4 = reinterpret_cast<const float4*>(Mc);
    float4 mA = Mc4[lane * 2];      // Mc[8l..8l+3]  (k=4l,4l+1 interleaved pairs)
    float4 mB = Mc4[lane * 2 + 1];  // Mc[8l+4..8l+7]
    float c0 = Mc[512], c1 = Mc[513];
    int base = blockIdx.x * 16 + wave * 4;
    #pragma unroll
    for (int it = 0; it < 4; ++it) {
        int rid = base + it;
        float4 v = *reinterpret_cast<const float4*>(x + (size_t)rid * DD + lane * 4);
        float a0 = v.x * mA.x + v.y * mA.z + v.z * mB.x + v.w * mB.z;
        float a1 = v.x * mA.y + v.y * mA.w + v.z * mB.y + v.w * mB.w;
        #pragma unroll
        for (int d = 32; d; d >>= 1) {
            a0 += __shfl_xor(a0, d);
            a1 += __shfl_xor(a1, d);
        }
        a0 += c0;
        a1 += c1;
        float n = sqrtf(a0 * a0 + a1 * a1);
        float scale = 1.f / (n + 1e-8f);
        float r = n * scale;
        #pragma unroll
        for (int i7 = 0; i7 < 7; ++i7) {
            float f = r / (r + 1e-8f);
            scale *= f;
            r *= f;
        }
        if (lane == 0) {
            float2 pv;
            pv.x = a0 * scale;
            pv.y = a1 * scale;
            *reinterpret_cast<float2*>(psi + (size_t)rid * 2) = pv;
        }
    }
}

// ---------------------------------------------------------------------------
// Kernel 1b: h0[b,j] = psi[b,S-1,:].hebb[j,:]  (+ moonlighted A/mask rows)
// ---------------------------------------------------------------------------
__global__ void h0_kernel(const float* __restrict__ psi, const float* __restrict__ hebb,
                          float* __restrict__ h0,
                          float* __restrict__ Ao, float* __restrict__ Mo, int arow0)
{
    int bid = blockIdx.x;
    if (bid >= BB) {
        int r = arow0 + (bid - BB);
        if (r < NROWS) amask_row(psi, Ao, Mo, r);
        return;
    }
    float2 pv = *reinterpret_cast<const float2*>(psi + ((size_t)bid * SS + SS - 1) * 2);
    for (int j = threadIdx.x; j < HH; j += blockDim.x)
        h0[(size_t)bid * HH + j] = pv.x * hebb[2 * j] + pv.y * hebb[2 * j + 1];
}

// ---------------------------------------------------------------------------
// Generic tiny-batch (B=8) GEMM: out[b,j] = R[b,j] + act( bias[j] + LN?(X)[b,:] . W[j,:] )
//   - optional LN on X (and optional second LN stage), staged in dynamic LDS
//   - optional LN on residual R (stats only; values read from global)
//   - act: 0 = none, 1 = silu
//   - G lanes (power of 2) cooperate per output j, shuffle-reduced.
//   - blocks with blockIdx.x >= mmBlocks moonlight as A/mask row writers.
// Block = 256 threads.
// ---------------------------------------------------------------------------
__global__ void head_mm(const float* __restrict__ X, int K,
                        const float* __restrict__ xlnw, const float* __restrict__ xlnb,
                        const float* __restrict__ xln2w, const float* __restrict__ xln2b,
                        const float* __restrict__ W, const float* __restrict__ bias,
                        const float* __restrict__ res,
                        const float* __restrict__ reslnw, const float* __restrict__ reslnb,
                        float* __restrict__ out, int J, int G, int act,
                        const float* __restrict__ psi,
                        float* __restrict__ Ao, float* __restrict__ Mo,
                        int mmBlocks, int arow0)
{
    const int bid = blockIdx.x;
    if (bid >= mmBlocks) {
        int r = arow0 + (bid - mmBlocks);
        if (r < NROWS) amask_row(psi, Ao, Mo, r);
        return;
    }

    extern __shared__ float sX[];           // 8*K floats when LN is active
    __shared__ float s_m[8], s_r[8], s_rm[8], s_rr[8];
    const int tid = threadIdx.x;
    const int row = tid >> 5, lane = tid & 31;   // 32 lanes per batch-row for stats
    const bool doLN = (xlnw != nullptr);
    const bool doRLN = (res != nullptr) && (reslnw != nullptr);

    if (doLN) {
        float s = 0.f, ss = 0.f;
        for (int k = lane; k < K; k += 32) {
            float v = X[row * K + k];
            s += v; ss += v * v;
        }
        for (int d = 16; d; d >>= 1) { s += __shfl_down(s, d); ss += __shfl_down(ss, d); }
        if (lane == 0) {
            float m = s / K;
            s_m[row] = m;
            s_r[row] = rsqrtf(ss / K - m * m + 1e-5f);
        }
    }
    if (doRLN) {
        float s = 0.f, ss = 0.f;
        for (int k = lane; k < J; k += 32) {
            float v = res[row * J + k];
            s += v; ss += v * v;
        }
        for (int d = 16; d; d >>= 1) { s += __shfl_down(s, d); ss += __shfl_down(ss, d); }
        if (lane == 0) {
            float m = s / J;
            s_rm[row] = m;
            s_rr[row] = rsqrtf(ss / J - m * m + 1e-5f);
        }
    }
    __syncthreads();

    if (doLN) {
        for (int idx = tid; idx < 8 * K; idx += 256) {
            int b = idx / K, k = idx - b * K;
            sX[idx] = (X[idx] - s_m[b]) * s_r[b] * xlnw[k] + xlnb[k];
        }
        __syncthreads();
        if (xln2w) {   // second LN stage (LN(LN(x)))
            float s = 0.f, ss = 0.f;
            for (int k = lane; k < K; k += 32) {
                float v = sX[row * K + k];
                s += v; ss += v * v;
            }
            for (int d = 16; d; d >>= 1) { s += __shfl_down(s, d); ss += __shfl_down(ss, d); }
            if (lane == 0) {
                float m = s / K;
                s_m[row] = m;
                s_r[row] = rsqrtf(ss / K - m * m + 1e-5f);
            }
            __syncthreads();
            for (int idx = tid; idx < 8 * K; idx += 256) {
                int b = idx / K, k = idx - b * K;
                sX[idx] = (sX[idx] - s_m[b]) * s_r[b] * xln2w[k] + xln2b[k];
            }
            __syncthreads();
        }
    }

    const float* __restrict__ Xp = doLN ? (const float*)sX : X;
    const int g = tid & (G - 1);
    const int jj = tid / G;
    const int j = bid * (256 / G) + jj;

    float acc[8] = {0.f, 0.f, 0.f, 0.f, 0.f, 0.f, 0.f, 0.f};
    if (j < J) {
        const float4* W4 = reinterpret_cast<const float4*>(W + (size_t)j * K);
        const int K4 = K >> 2;
        for (int i4 = g; i4 < K4; i4 += G) {
            float4 w4 = W4[i4];
            int k = i4 << 2;
            #pragma unroll
            for (int b = 0; b < 8; ++b) {
                float4 xv = *reinterpret_cast<const float4*>(Xp + b * K + k);
                acc[b] = fmaf(w4.x, xv.x, acc[b]);
                acc[b] = fmaf(w4.y, xv.y, acc[b]);
                acc[b] = fmaf(w4.z, xv.z, acc[b]);
                acc[b] = fmaf(w4.w, xv.w, acc[b]);
            }
        }
    }
    for (int d = G >> 1; d; d >>= 1) {
        #pragma unroll
        for (int b = 0; b < 8; ++b) acc[b] += __shfl_down(acc[b], d);
    }
    if (g == 0 && j < J) {
        float bs = bias ? bias[j] : 0.f;
        #pragma unroll
        for (int b = 0; b < 8; ++b) {
            float v = acc[b] + bs;
            if (act) v = v / (1.f + expf(-v));   // silu
            if (res) {
                float rv = res[(size_t)b * J + j];
                if (reslnw) rv = (rv - s_rm[b]) * s_rr[b] * reslnw[j] + reslnb[j];
                v += rv;
            }
            out[(size_t)b * J + j] = v;
        }
    }
}

// ---------------------------------------------------------------------------
extern "C" void kernel_launch(void* const* d_in, const int* in_sizes, int n_in,
                              void* d_out, int out_size, void* d_ws, size_t ws_size,
                              hipStream_t stream)
{
    const float* x      = (const float*)d_in[0];
    const float* proj_w = (const float*)d_in[1];
    const float* proj_b = (const float*)d_in[2];
    const float* pe     = (const float*)d_in[3];
    const float* hebb   = (const float*)d_in[4];
    const float* ai_w   = (const float*)d_in[5];
    const float* ai_b   = (const float*)d_in[6];
    const float* ao_w   = (const float*)d_in[7];
    const float* ao_b   = (const float*)d_in[8];
    const float* f1_w   = (const float*)d_in[9];
    const float* f1_b   = (const float*)d_in[10];
    const float* f2_w   = (const float*)d_in[11];
    const float* f2_b   = (const float*)d_in[12];
    const float* ln1w   = (const float*)d_in[13];
    const float* ln1b   = (const float*)d_in[14];
    const float* ln2w   = (const float*)d_in[15];
    const float* ln2b   = (const float*)d_in[16];
    const float* nAw    = (const float*)d_in[17];
    const float* nAb    = (const float*)d_in[18];
    const float* nBw    = (const float*)d_in[19];
    const float* nBb    = (const float*)d_in[20];
    const float* p1w    = (const float*)d_in[21];
    const float* p1b    = (const float*)d_in[22];
    const float* p2w    = (const float*)d_in[23];
    const float* p2b    = (const float*)d_in[24];

    float* out   = (float*)d_out;
    // output layout: preds(8) | A(B*S*S) | mask(B*S*S) | psi(B*S*2)
    float* preds = out;
    float* A     = out + 8;
    float* Mask  = out + 8 + (size_t)BB * SS * SS;
    float* Psi   = out + 8 + (size_t)2 * BB * SS * SS;

    float* ws = (float*)d_ws;
    float* Mc = ws;            // 514 (pad to 640)
    float* T  = ws + 640;      // 8x512 pre-LN state (starts as h0)
    float* V  = ws + 4736;     // 8x512
    float* T1 = ws + 8832;     // 8x512
    float* F  = ws + 12928;    // 8x2048
    float* P  = ws + 29312;    // 8x256

    compute_M<<<1, 1024, 0, stream>>>(proj_w, proj_b, pe, Mc);
    psi_kernel<<<NROWS / 16, 256, 0, stream>>>(x, Mc, Psi);

    // 15 carrier launches moonlight the 16384 A/mask rows (~1092 each).
    int ci = 0, arow = 0;
    auto nextq = [&]() { int q = 1092 + (ci < 4 ? 1 : 0); ++ci; return q; };

    {
        int q = nextq();
        h0_kernel<<<BB + q, 256, 0, stream>>>(Psi, hebb, T, A, Mask, arow);
        arow += q;
    }

    for (int l = 0; l < LL; ++l) {
        const float* pxw = l ? ln2w + (l - 1) * HH : nullptr;
        const float* pxb = l ? ln2b + (l - 1) * HH : nullptr;
        int q;
        // v = LN?(h) @ Wv^T + bv            (J=512, K=512, G=32 -> 64 mm blocks)
        q = nextq();
        head_mm<<<64 + q, 256, (pxw ? 8 * HH * 4 : 0), stream>>>(
            T, HH, pxw, pxb, nullptr, nullptr,
            ai_w + ((size_t)l * 3 * HH + 2 * HH) * HH, ai_b + l * 3 * HH + 2 * HH,
            nullptr, nullptr, nullptr, V, HH, 32, 0,
            Psi, A, Mask, 64, arow);
        arow += q;
        // t1 = LN?(T) + (v @ Wo^T + bo)     (J=512, K=512)
        q = nextq();
        head_mm<<<64 + q, 256, 0, stream>>>(
            V, HH, nullptr, nullptr, nullptr, nullptr,
            ao_w + (size_t)l * HH * HH, ao_b + l * HH,
            T, pxw, pxb, T1, HH, 32, 0,
            Psi, A, Mask, 64, arow);
        arow += q;
        // f = silu(LN(t1,ln1) @ W1^T + b1)  (J=2048, K=512, G=16 -> 128 mm blocks)
        q = nextq();
        head_mm<<<128 + q, 256, 8 * HH * 4, stream>>>(
            T1, HH, ln1w + l * HH, ln1b + l * HH, nullptr, nullptr,
            f1_w + (size_t)l * 4 * HH * HH, f1_b + l * 4 * HH,
            nullptr, nullptr, nullptr, F, 4 * HH, 16, 1,
            Psi, A, Mask, 128, arow);
        arow += q;
        // t2 = LN(t1,ln1) + (f @ W2^T + b2) (J=512, K=2048, G=64 -> 128 mm blocks)
        q = nextq();
        head_mm<<<128 + q, 256, 0, stream>>>(
            F, 4 * HH, nullptr, nullptr, nullptr, nullptr,
            f2_w + (size_t)l * HH * 4 * HH, f2_b + l * HH,
            T1, ln1w + l * HH, ln1b + l * HH, T, HH, 64, 0,
            Psi, A, Mask, 128, arow);
        arow += q;
    }
    // p = silu( LN(LN(t2,ln2[2]),normA) @ p1^T + p1_b )   (J=256, K=512)
    {
        int q = nextq();
        head_mm<<<32 + q, 256, 8 * HH * 4, stream>>>(
            T, HH, ln2w + 2 * HH, ln2b + 2 * HH, nAw, nAb,
            p1w, p1b, nullptr, nullptr, nullptr, P, HH / 2, 32, 1,
            Psi, A, Mask, 32, arow);
        arow += q;
    }
    // preds = LN(p,normB) @ p2^T + p2_b                   (J=1, K=256)
    {
        int q = nextq();
        head_mm<<<1 + q, 256, 8 * (HH / 2) * 4, stream>>>(
            P, HH / 2, nBw, nBb, nullptr, nullptr,
            p2w, p2b, nullptr, nullptr, nullptr, preds, 1, 32, 0,
            Psi, A, Mask, 1, arow);
        arow += q;
    }
}